// Round 1
// baseline (1128.426 us; speedup 1.0000x reference)
//
#include <hip/hip_runtime.h>

#define NN 50000
#define NE 500000
#define HD 128

typedef unsigned short ushort_t;
typedef __bf16 bf16x8 __attribute__((ext_vector_type(8)));
typedef float f32x4 __attribute__((ext_vector_type(4)));

static __device__ __forceinline__ unsigned short f2bf(float f) {
  unsigned int u = __float_as_uint(f);
  unsigned int r = (u + 0x7fffu + ((u >> 16) & 1u)) >> 16;  // RNE
  return (unsigned short)r;
}
static __device__ __forceinline__ float2 ldbf2(const unsigned short* p) {
  unsigned int u = *reinterpret_cast<const unsigned int*>(p);
  return make_float2(__uint_as_float(u << 16), __uint_as_float(u & 0xffff0000u));
}

// ---------------- CSR build ----------------
__global__ __launch_bounds__(256) void hist_kernel(const int* __restrict__ src, const int* __restrict__ dst,
                                                   int* __restrict__ deg_src, int* __restrict__ deg_dst, int E) {
  int e = blockIdx.x * 256 + threadIdx.x;
  if (e < E) {
    atomicAdd(&deg_dst[dst[e]], 1);
    atomicAdd(&deg_src[src[e]], 1);
  }
}

__global__ __launch_bounds__(1024) void scan_kernel(const int* __restrict__ deg_dst, const int* __restrict__ deg_src,
                                                    int* __restrict__ off_dst, int* __restrict__ cur_dst,
                                                    int* __restrict__ off_src, int* __restrict__ cur_src, int N) {
  const int* deg = blockIdx.x ? deg_src : deg_dst;
  int* off = blockIdx.x ? off_src : off_dst;
  int* cur = blockIdx.x ? cur_src : cur_dst;
  const int CH = (N + 1023) / 1024;
  int t = threadIdx.x;
  int base = t * CH;
  int sum = 0;
  for (int i = 0; i < CH; ++i) { int idx = base + i; if (idx < N) sum += deg[idx]; }
  __shared__ int ls[1024];
  ls[t] = sum;
  __syncthreads();
  for (int o = 1; o < 1024; o <<= 1) {
    int u = (t >= o) ? ls[t - o] : 0;
    __syncthreads();
    ls[t] += u;
    __syncthreads();
  }
  int run = ls[t] - sum;  // exclusive prefix of this thread's chunk
  for (int i = 0; i < CH; ++i) {
    int idx = base + i;
    if (idx < N) { off[idx] = run; cur[idx] = run; run += deg[idx]; }
  }
  if (t == 1023) off[N] = ls[1023];
}

__global__ __launch_bounds__(256) void scatter_kernel(const int* __restrict__ src, const int* __restrict__ dst,
                                                      int* __restrict__ cur_src, int* __restrict__ cur_dst,
                                                      int* __restrict__ eid_src, int* __restrict__ eid_dst, int E) {
  int e = blockIdx.x * 256 + threadIdx.x;
  if (e < E) {
    int p = atomicAdd(&cur_dst[dst[e]], 1); eid_dst[p] = e;
    int q = atomicAdd(&cur_src[src[e]], 1); eid_src[q] = e;
  }
}

// ---------------- fp32 -> bf16 convert ----------------
__global__ __launch_bounds__(256) void hconv_kernel(const float* __restrict__ h, ushort_t* __restrict__ hb, int total4) {
  int i = blockIdx.x * 256 + threadIdx.x;
  if (i >= total4) return;
  float4 v = reinterpret_cast<const float4*>(h)[i];
  ushort4 u = { f2bf(v.x), f2bf(v.y), f2bf(v.z), f2bf(v.w) };
  reinterpret_cast<ushort4*>(hb)[i] = u;
}

// ---------------- generic small-K MFMA GEMM: out = epi(A @ W^T + bias) ----------------
// MODE bits: 1 = relu, 2 = add resid (fp32 [nrows,OUTC]), 4 = out is bf16 (else fp32)
template <int K, int OUTC, int MODE>
__global__ __launch_bounds__(256) void gemm_kernel(const ushort_t* __restrict__ A, const float* __restrict__ W,
                                                   const float* __restrict__ bias, const float* __restrict__ resid,
                                                   void* __restrict__ out, float scale, int nrows) {
  constexpr int KP = K + 8;  // +16B pad per row: breaks LDS bank conflicts
  __shared__ __align__(16) ushort_t wlds[OUTC * KP];
  constexpr int NLOAD = OUTC * K / 4;
  for (int idx = threadIdx.x; idx < NLOAD; idx += 256) {
    int r = idx / (K / 4), c4 = idx % (K / 4);
    float4 wv = reinterpret_cast<const float4*>(W)[idx];
    ushort_t* d = &wlds[r * KP + c4 * 4];
    d[0] = f2bf(wv.x); d[1] = f2bf(wv.y); d[2] = f2bf(wv.z); d[3] = f2bf(wv.w);
  }
  __syncthreads();
  const int wave = threadIdx.x >> 6, lane = threadIdx.x & 63;
  const int row0 = (blockIdx.x * 4 + wave) * 16;
  if (row0 >= nrows) return;
  const int m = lane & 15, quad = lane >> 4;
  // A fragments: lane holds A[row0+m][kk*32 + quad*8 + j], j=0..7 (verified m91 layout)
  bf16x8 afrag[K / 32];
  {
    const ushort_t* ar = A + (size_t)(row0 + m) * K + quad * 8;
#pragma unroll
    for (int kk = 0; kk < K / 32; ++kk)
      afrag[kk] = *reinterpret_cast<const bf16x8*>(ar + kk * 32);
  }
  f32x4 acc[OUTC / 16] = {};
#pragma unroll
  for (int c = 0; c < OUTC / 16; ++c) {
    const ushort_t* wr = &wlds[(c * 16 + m) * KP + quad * 8];
#pragma unroll
    for (int kk = 0; kk < K / 32; ++kk) {
      bf16x8 bfrag = *reinterpret_cast<const bf16x8*>(wr + kk * 32);
      acc[c] = __builtin_amdgcn_mfma_f32_16x16x32_bf16(afrag[kk], bfrag, acc[c], 0, 0, 0);
    }
  }
#pragma unroll
  for (int c = 0; c < OUTC / 16; ++c) {
    int col = c * 16 + m;
    float bv = bias[col];
#pragma unroll
    for (int r = 0; r < 4; ++r) {
      int grow = row0 + quad * 4 + r;  // C/D layout: row=(lane>>4)*4+reg, col=lane&15
      float val = (acc[c][r] + bv) * scale;
      if constexpr (MODE & 1) val = fmaxf(val, 0.0f);
      if constexpr (MODE & 2) val += resid[(size_t)grow * OUTC + col];
      if constexpr (MODE & 4) ((ushort_t*)out)[(size_t)grow * OUTC + col] = f2bf(val);
      else ((float*)out)[(size_t)grow * OUTC + col] = val;
    }
  }
}

// ---------------- GINE aggregation + eattr passthrough copy ----------------
// wave-per-node over CSR-by-dst: z = h[n] + sum_e relu(h[src[e]] + eattr[e]); also out_eattr[e] = eattr[e]
__global__ __launch_bounds__(256) void agg_kernel(const float* __restrict__ h, const float* __restrict__ eattr,
                                                  const int* __restrict__ src, const int* __restrict__ off_dst,
                                                  const int* __restrict__ eid_dst, float* __restrict__ out_eattr,
                                                  ushort_t* __restrict__ z_bf, int N) {
  int wave = threadIdx.x >> 6, lane = threadIdx.x & 63;
  int n = blockIdx.x * 4 + wave;
  if (n >= N) return;
  int c2 = lane * 2;
  float a0 = 0.f, a1 = 0.f;
  int beg = off_dst[n], end = off_dst[n + 1];
  for (int i = beg; i < end; ++i) {
    int e = eid_dst[i];
    int s = src[e];
    float2 ea = *reinterpret_cast<const float2*>(eattr + (size_t)e * HD + c2);
    *reinterpret_cast<float2*>(out_eattr + (size_t)e * HD + c2) = ea;  // fused passthrough
    float2 hs = *reinterpret_cast<const float2*>(h + (size_t)s * HD + c2);
    a0 += fmaxf(hs.x + ea.x, 0.f);
    a1 += fmaxf(hs.y + ea.y, 0.f);
  }
  float2 hn = *reinterpret_cast<const float2*>(h + (size_t)n * HD + c2);
  ushort2 u = { f2bf(hn.x + a0), f2bf(hn.y + a1) };
  *reinterpret_cast<ushort2*>(z_bf + (size_t)n * HD + c2) = u;
}

// ---------------- sparse attention, wave-per-node over CSR-by-src, online softmax ----------------
// lane layout: head = lane>>3 (8 lanes/head), each lane owns dims {2j, 2j+1}, j = lane&7; col = 2*lane
__global__ __launch_bounds__(256) void attn_kernel(const ushort_t* __restrict__ qb, const ushort_t* __restrict__ kb,
                                                   const ushort_t* __restrict__ vb, const int* __restrict__ off_src,
                                                   const int* __restrict__ eid_src, const int* __restrict__ dst,
                                                   const float* __restrict__ h, float* __restrict__ X2, int N) {
  int wave = threadIdx.x >> 6, lane = threadIdx.x & 63;
  int n = blockIdx.x * 4 + wave;
  if (n >= N) return;
  int c2 = lane * 2;
  float2 qv = ldbf2(qb + (size_t)n * HD + c2);
  float m = -__builtin_inff(), l = 0.f, a0 = 0.f, a1 = 0.f;
  int beg = off_src[n], end = off_src[n + 1];
  for (int i = beg; i < end; ++i) {
    int e = eid_src[i];
    int d = dst[e];
    float2 kd = ldbf2(kb + (size_t)d * HD + c2);
    float s = qv.x * kd.x + qv.y * kd.y;
    s += __shfl_xor(s, 1, 64);
    s += __shfl_xor(s, 2, 64);
    s += __shfl_xor(s, 4, 64);  // all 8 lanes of the head now hold the full dot
    float2 vd = ldbf2(vb + (size_t)d * HD + c2);
    float nm = fmaxf(m, s);
    float al = __expf(m - nm);  // m=-inf first iter -> 0
    float p = __expf(s - nm);
    l = l * al + p;
    a0 = a0 * al + p * vd.x;
    a1 = a1 * al + p * vd.y;
    m = nm;
  }
  float inv = (end > beg) ? 1.0f / l : 0.f;
  size_t base = (size_t)n * HD + c2;
  float2 hv = *reinterpret_cast<const float2*>(h + base);
  float2 o = make_float2(hv.x + a0 * inv, hv.y + a1 * inv);
  *reinterpret_cast<float2*>(X2 + base) = o;
}

// ---------------- BN column stats ----------------
__global__ __launch_bounds__(256) void stats_kernel(const float* __restrict__ X, float* __restrict__ sums,
                                                    float* __restrict__ sumsq, int N) {
  int col = threadIdx.x & 127, half = threadIdx.x >> 7;
  float s = 0.f, s2 = 0.f;
  for (int r = blockIdx.x * 2 + half; r < N; r += gridDim.x * 2) {
    float v = X[(size_t)r * HD + col];
    s += v;
    s2 += v * v;
  }
  __shared__ float ls[256], ls2[256];
  ls[threadIdx.x] = s;
  ls2[threadIdx.x] = s2;
  __syncthreads();
  if (half == 0) {
    s += ls[threadIdx.x + 128];
    s2 += ls2[threadIdx.x + 128];
    atomicAdd(&sums[col], s);
    atomicAdd(&sumsq[col], s2);
  }
}

__global__ void coeff_kernel(const float* __restrict__ sums, const float* __restrict__ sumsq,
                             const float* __restrict__ g, const float* __restrict__ b, float* __restrict__ ab, int N) {
  int c = threadIdx.x;  // 128
  float inv_n = 1.0f / (float)N;
  float mu = sums[c] * inv_n;
  float var = sumsq[c] * inv_n - mu * mu;
  float a = g[c] * rsqrtf(var + 1e-5f);
  ab[c] = a;
  ab[128 + c] = b[c] - mu * a;
}

// hc = bn1(X1) + bn2(X2), write fp32 + bf16
__global__ __launch_bounds__(256) void combine_kernel(const float* __restrict__ X1, const float* __restrict__ X2,
                                                      const float* __restrict__ ab1, const float* __restrict__ ab2,
                                                      float* __restrict__ hc_f, ushort_t* __restrict__ hc_b, int total4) {
  int i = blockIdx.x * 256 + threadIdx.x;
  if (i >= total4) return;
  float4 x1 = reinterpret_cast<const float4*>(X1)[i];
  float4 x2 = reinterpret_cast<const float4*>(X2)[i];
  int c = (i * 4) & 127;
  float4 r;
  r.x = x1.x * ab1[c + 0] + ab1[128 + c + 0] + x2.x * ab2[c + 0] + ab2[128 + c + 0];
  r.y = x1.y * ab1[c + 1] + ab1[128 + c + 1] + x2.y * ab2[c + 1] + ab2[128 + c + 1];
  r.z = x1.z * ab1[c + 2] + ab1[128 + c + 2] + x2.z * ab2[c + 2] + ab2[128 + c + 2];
  r.w = x1.w * ab1[c + 3] + ab1[128 + c + 3] + x2.w * ab2[c + 3] + ab2[128 + c + 3];
  reinterpret_cast<float4*>(hc_f)[i] = r;
  ushort4 u = { f2bf(r.x), f2bf(r.y), f2bf(r.z), f2bf(r.w) };
  reinterpret_cast<ushort4*>(hc_b)[i] = u;
}

__global__ __launch_bounds__(256) void final_kernel(const float* __restrict__ X3, const float* __restrict__ ab,
                                                    float* __restrict__ out, int total4) {
  int i = blockIdx.x * 256 + threadIdx.x;
  if (i >= total4) return;
  float4 x = reinterpret_cast<const float4*>(X3)[i];
  int c = (i * 4) & 127;
  float4 r;
  r.x = x.x * ab[c + 0] + ab[128 + c + 0];
  r.y = x.y * ab[c + 1] + ab[128 + c + 1];
  r.z = x.z * ab[c + 2] + ab[128 + c + 2];
  r.w = x.w * ab[c + 3] + ab[128 + c + 3];
  reinterpret_cast<float4*>(out)[i] = r;
}

extern "C" void kernel_launch(void* const* d_in, const int* in_sizes, int n_in,
                              void* d_out, int out_size, void* d_ws, size_t ws_size,
                              hipStream_t stream) {
  const float* h = (const float*)d_in[0];
  const float* eattr = (const float*)d_in[1];
  const int* src = (const int*)d_in[2];
  const int* dst = (const int*)d_in[3];
  const float* gin_w1 = (const float*)d_in[4];
  const float* gin_b1 = (const float*)d_in[5];
  const float* gin_w2 = (const float*)d_in[6];
  const float* gin_b2 = (const float*)d_in[7];
  const float* wq = (const float*)d_in[8];
  const float* bq = (const float*)d_in[9];
  const float* wk = (const float*)d_in[10];
  const float* bk = (const float*)d_in[11];
  const float* wv = (const float*)d_in[12];
  const float* bv = (const float*)d_in[13];
  const float* nl_g = (const float*)d_in[14];
  const float* nl_b = (const float*)d_in[15];
  const float* na_g = (const float*)d_in[16];
  const float* na_b = (const float*)d_in[17];
  const float* no_g = (const float*)d_in[18];
  const float* no_b = (const float*)d_in[19];
  const float* ffn1_w = (const float*)d_in[20];
  const float* ffn1_b = (const float*)d_in[21];
  const float* ffn2_w = (const float*)d_in[22];
  const float* ffn2_b = (const float*)d_in[23];

  const int N = NN, E = NE;
  char* ws = (char*)d_ws;
  size_t off = 0;
  auto alloc = [&](size_t bytes) -> void* {
    void* p = ws + off;
    off += (bytes + 255) & ~(size_t)255;
    return p;
  };

  ushort_t* h_bf = (ushort_t*)alloc((size_t)N * HD * 2);
  ushort_t* q_bf = (ushort_t*)alloc((size_t)N * HD * 2);
  ushort_t* k_bf = (ushort_t*)alloc((size_t)N * HD * 2);
  ushort_t* v_bf = (ushort_t*)alloc((size_t)N * HD * 2);
  ushort_t* z_bf = (ushort_t*)alloc((size_t)N * HD * 2);
  ushort_t* mid1 = (ushort_t*)alloc((size_t)N * HD * 2);
  ushort_t* hc_bf = (ushort_t*)alloc((size_t)N * HD * 2);
  ushort_t* mid2 = (ushort_t*)alloc((size_t)N * 256 * 2);
  float* X1 = (float*)alloc((size_t)N * HD * 4);
  float* X2 = (float*)alloc((size_t)N * HD * 4);
  float* X3 = (float*)alloc((size_t)N * HD * 4);
  float* hc_f = (float*)alloc((size_t)N * HD * 4);
  // ---- zero-init region (one memset) ----
  int* deg_dst = (int*)alloc((size_t)N * 4);
  int* deg_src = (int*)alloc((size_t)N * 4);
  float* stats = (float*)alloc(6 * 128 * 4);  // sums1,sq1,sums2,sq2,sums3,sq3
  size_t zero_bytes = (size_t)((char*)(stats + 6 * 128) - (char*)deg_dst);
  // ---- end zero region ----
  int* off_dst = (int*)alloc((size_t)(N + 1) * 4);
  int* off_src = (int*)alloc((size_t)(N + 1) * 4);
  int* cur_dst = (int*)alloc((size_t)N * 4);
  int* cur_src = (int*)alloc((size_t)N * 4);
  int* eid_dst = (int*)alloc((size_t)E * 4);
  int* eid_src = (int*)alloc((size_t)E * 4);
  float* ab1 = (float*)alloc(256 * 4);
  float* ab2 = (float*)alloc(256 * 4);
  float* ab3 = (float*)alloc(256 * 4);

  float* sums1 = stats, *sq1 = stats + 128;
  float* sums2 = stats + 256, *sq2 = stats + 384;
  float* sums3 = stats + 512, *sq3 = stats + 640;

  float* out_hc = (float*)d_out;
  float* out_eattr = (float*)d_out + (size_t)N * HD;

  hipMemsetAsync(deg_dst, 0, zero_bytes, stream);

  const int egrid = (E + 255) / 256;
  hist_kernel<<<egrid, 256, 0, stream>>>(src, dst, deg_src, deg_dst, E);
  scan_kernel<<<2, 1024, 0, stream>>>(deg_dst, deg_src, off_dst, cur_dst, off_src, cur_src, N);
  scatter_kernel<<<egrid, 256, 0, stream>>>(src, dst, cur_src, cur_dst, eid_src, eid_dst, E);

  const int total4 = N * HD / 4;
  const int cgrid = (total4 + 255) / 256;
  hconv_kernel<<<cgrid, 256, 0, stream>>>(h, h_bf, total4);

  const int ggrid = (N / 16 + 3) / 4;
  const float scale = 0.25f;  // DH^-0.5
  gemm_kernel<128, 128, 4><<<ggrid, 256, 0, stream>>>(h_bf, wq, bq, nullptr, q_bf, scale, N);
  gemm_kernel<128, 128, 4><<<ggrid, 256, 0, stream>>>(h_bf, wk, bk, nullptr, k_bf, 1.0f, N);
  gemm_kernel<128, 128, 4><<<ggrid, 256, 0, stream>>>(h_bf, wv, bv, nullptr, v_bf, 1.0f, N);

  agg_kernel<<<N / 4, 256, 0, stream>>>(h, eattr, src, off_dst, eid_dst, out_eattr, z_bf, N);
  gemm_kernel<128, 128, 5><<<ggrid, 256, 0, stream>>>(z_bf, gin_w1, gin_b1, nullptr, mid1, 1.0f, N);  // relu, bf16
  gemm_kernel<128, 128, 2><<<ggrid, 256, 0, stream>>>(mid1, gin_w2, gin_b2, h, X1, 1.0f, N);          // +h, fp32

  attn_kernel<<<N / 4, 256, 0, stream>>>(q_bf, k_bf, v_bf, off_src, eid_src, dst, h, X2, N);

  stats_kernel<<<256, 256, 0, stream>>>(X1, sums1, sq1, N);
  stats_kernel<<<256, 256, 0, stream>>>(X2, sums2, sq2, N);
  coeff_kernel<<<1, 128, 0, stream>>>(sums1, sq1, nl_g, nl_b, ab1, N);
  coeff_kernel<<<1, 128, 0, stream>>>(sums2, sq2, na_g, na_b, ab2, N);
  combine_kernel<<<cgrid, 256, 0, stream>>>(X1, X2, ab1, ab2, hc_f, hc_bf, total4);

  gemm_kernel<128, 256, 5><<<ggrid, 256, 0, stream>>>(hc_bf, ffn1_w, ffn1_b, nullptr, mid2, 1.0f, N);  // relu, bf16
  gemm_kernel<256, 128, 2><<<ggrid, 256, 0, stream>>>(mid2, ffn2_w, ffn2_b, hc_f, X3, 1.0f, N);        // +hc, fp32

  stats_kernel<<<256, 256, 0, stream>>>(X3, sums3, sq3, N);
  coeff_kernel<<<1, 128, 0, stream>>>(sums3, sq3, no_g, no_b, ab3, N);
  final_kernel<<<cgrid, 256, 0, stream>>>(X3, ab3, out_hc, total4);
}